// Round 3
// baseline (202.148 us; speedup 1.0000x reference)
//
#include <hip/hip_runtime.h>
#include <math.h>

typedef __attribute__((ext_vector_type(8))) short short8;
typedef __attribute__((ext_vector_type(4))) float f32x4;
typedef unsigned short ushort_t;

#define TSEQ   4096
#define NBATCH 4
#define DMODEL 768
#define HS     64
#define NQT    (TSEQ/16)      // 256 q-tiles per batch

static __device__ __forceinline__ ushort_t f2bf(float f) {
  union { float f; unsigned u; } v; v.f = f;
  unsigned r = v.u + 0x7fffu + ((v.u >> 16) & 1u);   // RNE
  return (ushort_t)(r >> 16);
}

#define MFMA16(a,b,c) __builtin_amdgcn_mfma_f32_16x16x32_bf16((a),(b),(c),0,0,0)

// ---------------- W prep: Wt[n'=m*64+n][k] bf16 (transposed) ----------------
__global__ __launch_bounds__(256) void wprep(
    const float* __restrict__ Wq, const float* __restrict__ Wk,
    const float* __restrict__ Wv, ushort_t* __restrict__ Wt)
{
  const int np = blockIdx.x;            // 0..191
  const int m = np >> 6, n = np & 63;
  const float* W = (m == 0) ? Wq : (m == 1) ? Wk : Wv;
  for (int kk = threadIdx.x; kk < DMODEL; kk += 256)
    Wt[(size_t)np * DMODEL + kk] = f2bf(W[(size_t)kk * HS + n]);
}

// ---------------- QKV projection (MFMA), wave-autonomous ----------------
// 2048 waves = 512 blocks. Wave gw: rows (gw>>1)*16 .. +15, n-half gw&1
// (6 n-tiles of the 12). No barriers; x and Wt read direct from global.
__global__ __launch_bounds__(256) void qkv_mfma(
    const float* __restrict__ x, const ushort_t* __restrict__ Wt,
    ushort_t* __restrict__ q, ushort_t* __restrict__ kO, ushort_t* __restrict__ vT)
{
  __shared__ __align__(16) float vls[4][16 * 68];   // wave-private v-transpose buf

  const int tid  = threadIdx.x;
  const int w    = tid >> 6, lane = tid & 63;
  const int l16  = lane & 15, quad = lane >> 4;
  const int gw   = blockIdx.x * 4 + w;              // 0..2047
  const int rowBase = (gw >> 1) * 16;
  const int nHalf   = gw & 1;

  const float* xg = x + (size_t)(rowBase + l16) * DMODEL + quad * 8;
  const ushort_t* wb = Wt + (size_t)(nHalf * 96 + l16) * DMODEL + quad * 8;

  f32x4 acc[6];
#pragma unroll
  for (int nt = 0; nt < 6; nt++) acc[nt] = (f32x4){0.f, 0.f, 0.f, 0.f};

#pragma unroll 4
  for (int ks = 0; ks < DMODEL / 32; ks++) {
    const float4 xa = *(const float4*)(xg + ks * 32);
    const float4 xb = *(const float4*)(xg + ks * 32 + 4);
    short8 af;
    af[0]=f2bf(xa.x); af[1]=f2bf(xa.y); af[2]=f2bf(xa.z); af[3]=f2bf(xa.w);
    af[4]=f2bf(xb.x); af[5]=f2bf(xb.y); af[6]=f2bf(xb.z); af[7]=f2bf(xb.w);
#pragma unroll
    for (int nt = 0; nt < 6; nt++) {
      const short8 bf = *(const short8*)(wb + (size_t)nt * 16 * DMODEL + ks * 32);
      acc[nt] = MFMA16(af, bf, acc[nt]);
    }
  }

  // epilogue: C-frag row = quad*4+r, col = l16 within each 16-col tile
#pragma unroll
  for (int nt = 0; nt < 6; nt++) {
    const int gnt = nHalf * 6 + nt;
    const int mat = gnt >> 2;            // 0=q 1=k 2=v (wave-uniform)
    const int nc0 = (gnt & 3) * 16;
#pragma unroll
    for (int r = 0; r < 4; r++) {
      const float val = acc[nt][r];
      const int trow = rowBase + quad * 4 + r;
      const int col  = nc0 + l16;
      if (mat == 0)      q [(size_t)trow * HS + col] = f2bf(val * 0.125f);
      else if (mat == 1) kO[(size_t)trow * HS + col] = f2bf(val);
      else               vls[w][(quad * 4 + r) * 68 + col] = val;
    }
  }
  if (nHalf == 1) {                      // v-transpose (wave-private, no barrier)
    const int bb = rowBase >> 12;
    const int t0 = rowBase & (TSEQ - 1);
    const int d  = lane;
    short8 p0, p1;
#pragma unroll
    for (int i = 0; i < 8; i++)  p0[i] = (short)f2bf(vls[w][i * 68 + d]);
#pragma unroll
    for (int i = 0; i < 8; i++)  p1[i] = (short)f2bf(vls[w][(8 + i) * 68 + d]);
    ushort_t* dst = vT + ((size_t)bb * HS + d) * TSEQ + t0;
    *(short8*)(dst)     = p0;
    *(short8*)(dst + 8) = p1;
  }
}

// ---------------- causal flash attention (MFMA), no K/V LDS ----------------
// grid B*NQT=1024 blocks (big q-tiles first), 256 thr. 16 q-rows per block;
// 4 waves split 64-key tiles; K/V frags direct from global (L2-resident);
// P via wave-private LDS (aliased into merge buffer); merge at end.
#define PP 72                            // P LDS pitch (bf16), 16 x 72

__global__ __launch_bounds__(256) void attn_mfma(
    const ushort_t* __restrict__ q, const ushort_t* __restrict__ k,
    const ushort_t* __restrict__ vT, float* __restrict__ out)
{
  __shared__ __align__(16) float pool[4][1088];   // per-wave: P (2304 B) then O-merge (16x68 f32)
  __shared__ float sM[4][16];
  __shared__ float sL[4][16];

  const int idx   = blockIdx.x;
  const int b     = idx & 3;
  const int j     = (NQT - 1) - (idx >> 2);   // descending work order
  const int tbase = j * 16;
  const int w     = threadIdx.x >> 6;
  const int lane  = threadIdx.x & 63;
  const int l16   = lane & 15;
  const int quad  = lane >> 4;

  const ushort_t* qg = q  + ((size_t)b * TSEQ + tbase) * HS;
  const ushort_t* kg = k  + (size_t)b * TSEQ * HS;
  const ushort_t* vg = vT + (size_t)b * HS * TSEQ;

  ushort_t* Pw = (ushort_t*)&pool[w][0];

  // Q fragments (q pre-scaled by 1/8 in producer)
  const short8 qf0 = *(const short8*)(qg + l16 * HS +      quad * 8);
  const short8 qf1 = *(const short8*)(qg + l16 * HS + 32 + quad * 8);

  f32x4 o0 = {0.f,0.f,0.f,0.f}, o1 = o0, o2 = o0, o3 = o0;
  float mrow[4] = {-INFINITY, -INFINITY, -INFINITY, -INFINITY};
  float lrow[4] = {0.f, 0.f, 0.f, 0.f};

  const int nkt = (j >> 2) + 1;               // 64-key tiles incl. diagonal
  for (int kt = w; kt < nkt; kt += 4) {
    const int k0 = kt * 64;
    // ---- S = Q K^T  [16 rows x 64 keys], K frags direct from global ----
    f32x4 s[4];
#pragma unroll
    for (int c = 0; c < 4; c++) {
      s[c] = (f32x4){0.f, 0.f, 0.f, 0.f};
      const ushort_t* kr = kg + (size_t)(k0 + c * 16 + l16) * HS + quad * 8;
      const short8 kf0 = *(const short8*)(kr);
      const short8 kf1 = *(const short8*)(kr + 32);
      s[c] = MFMA16(qf0, kf0, s[c]);
      s[c] = MFMA16(qf1, kf1, s[c]);
    }
    // ---- causal mask (only the diagonal tile; wave-uniform branch) ----
    if (k0 + 63 > tbase) {
#pragma unroll
      for (int c = 0; c < 4; c++) {
        const int key = k0 + c * 16 + l16;
#pragma unroll
        for (int r = 0; r < 4; r++)
          s[c][r] = (key <= tbase + quad * 4 + r) ? s[c][r] : -INFINITY;
      }
    }
    // ---- online softmax over 64 keys (rows quad*4+r) ----
    float tm[4], al[4];
#pragma unroll
    for (int r = 0; r < 4; r++)
      tm[r] = fmaxf(fmaxf(s[0][r], s[1][r]), fmaxf(s[2][r], s[3][r]));
#pragma unroll
    for (int mk = 1; mk < 16; mk <<= 1)
#pragma unroll
      for (int r = 0; r < 4; r++) tm[r] = fmaxf(tm[r], __shfl_xor(tm[r], mk));
#pragma unroll
    for (int r = 0; r < 4; r++) {
      const float mn = fmaxf(mrow[r], tm[r]);
      al[r] = __expf(mrow[r] - mn);
      mrow[r] = mn;
#pragma unroll
      for (int c = 0; c < 4; c++) s[c][r] = __expf(s[c][r] - mn);
    }
    float ps[4];
#pragma unroll
    for (int r = 0; r < 4; r++) ps[r] = (s[0][r] + s[1][r]) + (s[2][r] + s[3][r]);
#pragma unroll
    for (int mk = 1; mk < 16; mk <<= 1)
#pragma unroll
      for (int r = 0; r < 4; r++) ps[r] += __shfl_xor(ps[r], mk);
#pragma unroll
    for (int r = 0; r < 4; r++) lrow[r] = lrow[r] * al[r] + ps[r];
    // ---- P -> LDS (C-layout in, A-layout out), rescale O ----
#pragma unroll
    for (int c = 0; c < 4; c++)
#pragma unroll
      for (int r = 0; r < 4; r++)
        Pw[(quad * 4 + r) * PP + c * 16 + l16] = f2bf(s[c][r]);
#pragma unroll
    for (int r = 0; r < 4; r++) {
      o0[r] *= al[r]; o1[r] *= al[r]; o2[r] *= al[r]; o3[r] *= al[r];
    }
    // ---- O += P V, V frags direct from global (vT layout) ----
    const short8 pf0 = *(const short8*)(Pw + l16 * PP +      quad * 8);
    const short8 pf1 = *(const short8*)(Pw + l16 * PP + 32 + quad * 8);
    {
      const ushort_t* vr = vg + (size_t)l16 * TSEQ + k0 + quad * 8;
      short8 vf;
      vf = *(const short8*)(vr);                      o0 = MFMA16(pf0, vf, o0);
      vf = *(const short8*)(vr + 32);                 o0 = MFMA16(pf1, vf, o0);
      vf = *(const short8*)(vr + 16 * TSEQ);          o1 = MFMA16(pf0, vf, o1);
      vf = *(const short8*)(vr + 16 * TSEQ + 32);     o1 = MFMA16(pf1, vf, o1);
      vf = *(const short8*)(vr + 32 * TSEQ);          o2 = MFMA16(pf0, vf, o2);
      vf = *(const short8*)(vr + 32 * TSEQ + 32);     o2 = MFMA16(pf1, vf, o2);
      vf = *(const short8*)(vr + 48 * TSEQ);          o3 = MFMA16(pf0, vf, o3);
      vf = *(const short8*)(vr + 48 * TSEQ + 32);     o3 = MFMA16(pf1, vf, o3);
    }
  }

  // ---- merge 4 key-split partials per row ----
  if (l16 == 0) {
#pragma unroll
    for (int r = 0; r < 4; r++) {
      sM[w][quad * 4 + r] = mrow[r];
      sL[w][quad * 4 + r] = lrow[r];
    }
  }
  float* Ow = &pool[w][0];                 // overwrites Pw (wave-private, in-order)
#pragma unroll
  for (int r = 0; r < 4; r++) {
    Ow[(quad * 4 + r) * 68 + l16     ] = o0[r];
    Ow[(quad * 4 + r) * 68 + l16 + 16] = o1[r];
    Ow[(quad * 4 + r) * 68 + l16 + 32] = o2[r];
    Ow[(quad * 4 + r) * 68 + l16 + 48] = o3[r];
  }
  __syncthreads();

  const int row = threadIdx.x >> 4;       // 0..15
  const int d4  = threadIdx.x & 15;       // 4 dims each
  const float M = fmaxf(fmaxf(sM[0][row], sM[1][row]),
                        fmaxf(sM[2][row], sM[3][row]));
  float den = 0.f;
  float4 num = make_float4(0.f, 0.f, 0.f, 0.f);
#pragma unroll
  for (int ww = 0; ww < 4; ww++) {
    const float a = __expf(sM[ww][row] - M);      // zero-trip wave: weight 0
    den += sL[ww][row] * a;
    const float4 val = *(const float4*)(&pool[ww][row * 68 + d4 * 4]);
    num.x += a * val.x; num.y += a * val.y; num.z += a * val.z; num.w += a * val.w;
  }
  const float inv = 1.f / den;
  *(float4*)(out + ((size_t)b * TSEQ + tbase + row) * HS + d4 * 4) =
      make_float4(num.x * inv, num.y * inv, num.z * inv, num.w * inv);
}

extern "C" void kernel_launch(void* const* d_in, const int* in_sizes, int n_in,
                              void* d_out, int out_size, void* d_ws, size_t ws_size,
                              hipStream_t stream) {
  const float* x  = (const float*)d_in[0];
  const float* Wq = (const float*)d_in[1];
  const float* Wk = (const float*)d_in[2];
  const float* Wv = (const float*)d_in[3];
  float* out = (float*)d_out;

  // ws: Wt (288 KB) | q (2 MB) | k (2 MB) | vT (2 MB)
  char* ws = (char*)d_ws;
  ushort_t* Wt = (ushort_t*)ws;
  ushort_t* qb = (ushort_t*)(ws + 294912);
  ushort_t* kb = (ushort_t*)(ws + 294912 + 2097152);
  ushort_t* vb = (ushort_t*)(ws + 294912 + 2 * 2097152);

  wprep<<<192, 256, 0, stream>>>(Wq, Wk, Wv, Wt);
  qkv_mfma<<<512, 256, 0, stream>>>(x, Wt, qb, kb, vb);
  attn_mfma<<<NBATCH * NQT, 256, 0, stream>>>(qb, kb, vb, out);
}

// Round 4
// 193.509 us; speedup vs baseline: 1.0446x; 1.0446x over previous
//
#include <hip/hip_runtime.h>
#include <math.h>

typedef __attribute__((ext_vector_type(8))) short short8;
typedef __attribute__((ext_vector_type(4))) float f32x4;
typedef unsigned short ushort_t;

#define TSEQ   4096
#define NBATCH 4
#define DMODEL 768
#define HS     64

static __device__ __forceinline__ ushort_t f2bf(float f) {
  union { float f; unsigned u; } v; v.f = f;
  unsigned r = v.u + 0x7fffu + ((v.u >> 16) & 1u);   // RNE
  return (ushort_t)(r >> 16);
}

#define MFMA16(a,b,c) __builtin_amdgcn_mfma_f32_16x16x32_bf16((a),(b),(c),0,0,0)

// ---------------- W prep: Wt[n'=m*64+n][k] bf16 (transposed) ----------------
__global__ __launch_bounds__(256) void wprep(
    const float* __restrict__ Wq, const float* __restrict__ Wk,
    const float* __restrict__ Wv, ushort_t* __restrict__ Wt)
{
  const int np = blockIdx.x;            // 0..191
  const int m = np >> 6, n = np & 63;
  const float* W = (m == 0) ? Wq : (m == 1) ? Wk : Wv;
  for (int kk = threadIdx.x; kk < DMODEL; kk += 256)
    Wt[(size_t)np * DMODEL + kk] = f2bf(W[(size_t)kk * HS + n]);
}

// ---------------- QKV projection: M=64 x N=96 tiles, grid 512 ----------------
// 4 waves: (mhalf 2) x (nsplit 2, 48 cols = 3 ntiles). BK=64, LDS double-buffer
// for A (fp32->bf16 reg convert), B-frags direct from L2-resident Wt.
__global__ __launch_bounds__(256) void qkv_mfma(
    const float* __restrict__ x, const ushort_t* __restrict__ Wt,
    ushort_t* __restrict__ q, ushort_t* __restrict__ kO, ushort_t* __restrict__ vT)
{
  __shared__ __align__(16) ushort_t Abuf[2][64 * 72];   // pitch 72 = 144B (odd*16)

  const int tid  = threadIdx.x;
  const int w    = tid >> 6, lane = tid & 63;
  const int l16  = lane & 15, quad = lane >> 4;
  const int Mblk = blockIdx.x >> 1, nHalf = blockIdx.x & 1;
  const int M0   = Mblk * 64;
  const int mh   = w >> 1, ns = w & 1;
  const float* xg = x + (size_t)M0 * DMODEL;
  const ushort_t* wbase = Wt + (size_t)(nHalf * 96 + ns * 48 + l16) * DMODEL + quad * 8;

  const int srow = tid >> 2, scol = (tid & 3) * 16;     // staging: 4 thr/row
  const float* xs = xg + (size_t)srow * DMODEL + scol;

  f32x4 acc[2][3];
#pragma unroll
  for (int a = 0; a < 2; a++)
#pragma unroll
    for (int c = 0; c < 3; c++) acc[a][c] = (f32x4){0.f, 0.f, 0.f, 0.f};

  float4 pr0 = *(const float4*)(xs);
  float4 pr1 = *(const float4*)(xs + 4);
  float4 pr2 = *(const float4*)(xs + 8);
  float4 pr3 = *(const float4*)(xs + 12);

  for (int ks = 0; ks < DMODEL / 64; ks++) {
    ushort_t* Ab = &Abuf[ks & 1][0];
    {
      short8 pa, pb;
      pa[0]=f2bf(pr0.x); pa[1]=f2bf(pr0.y); pa[2]=f2bf(pr0.z); pa[3]=f2bf(pr0.w);
      pa[4]=f2bf(pr1.x); pa[5]=f2bf(pr1.y); pa[6]=f2bf(pr1.z); pa[7]=f2bf(pr1.w);
      pb[0]=f2bf(pr2.x); pb[1]=f2bf(pr2.y); pb[2]=f2bf(pr2.z); pb[3]=f2bf(pr2.w);
      pb[4]=f2bf(pr3.x); pb[5]=f2bf(pr3.y); pb[6]=f2bf(pr3.z); pb[7]=f2bf(pr3.w);
      *(short8*)(Ab + srow * 72 + scol)     = pa;
      *(short8*)(Ab + srow * 72 + scol + 8) = pb;
    }
    if (ks < DMODEL / 64 - 1) {          // prefetch next chunk (HBM latency hide)
      const float* xn = xs + (ks + 1) * 64;
      pr0 = *(const float4*)(xn);
      pr1 = *(const float4*)(xn + 4);
      pr2 = *(const float4*)(xn + 8);
      pr3 = *(const float4*)(xn + 12);
    }
    __syncthreads();                     // single barrier: dbuf makes it safe
#pragma unroll
    for (int kc = 0; kc < 2; kc++) {
      const int kk = ks * 64 + kc * 32;
      const short8 bf0 = *(const short8*)(wbase + kk);
      const short8 bf1 = *(const short8*)(wbase + 16 * DMODEL + kk);
      const short8 bf2 = *(const short8*)(wbase + 32 * DMODEL + kk);
      const short8 af0 = *(const short8*)(Ab + (mh * 32 + l16) * 72      + kc * 32 + quad * 8);
      const short8 af1 = *(const short8*)(Ab + (mh * 32 + 16 + l16) * 72 + kc * 32 + quad * 8);
      acc[0][0] = MFMA16(af0, bf0, acc[0][0]);
      acc[0][1] = MFMA16(af0, bf1, acc[0][1]);
      acc[0][2] = MFMA16(af0, bf2, acc[0][2]);
      acc[1][0] = MFMA16(af1, bf0, acc[1][0]);
      acc[1][1] = MFMA16(af1, bf1, acc[1][1]);
      acc[1][2] = MFMA16(af1, bf2, acc[1][2]);
    }
  }

  // ---- epilogue: q/k direct stores; v via block transpose (nHalf==1 only) ----
#pragma unroll
  for (int nt = 0; nt < 3; nt++) {
    const int gnt = nHalf * 6 + ns * 3 + nt;
    const int mat = gnt >> 2;            // 0=q 1=k 2=v  (wave-uniform)
    if (mat <= 1) {
      const int col = (gnt & 3) * 16 + l16;
#pragma unroll
      for (int mt = 0; mt < 2; mt++) {
#pragma unroll
        for (int r = 0; r < 4; r++) {
          const float val = acc[mt][nt][r];
          const int trow = M0 + mh * 32 + mt * 16 + quad * 4 + r;
          if (mat == 0) q [(size_t)trow * HS + col] = f2bf(val * 0.125f);
          else          kO[(size_t)trow * HS + col] = f2bf(val);
        }
      }
    }
  }
  if (nHalf == 1) {
    __syncthreads();                     // all Abuf reads done; reuse as vls
    float* vls = (float*)&Abuf[0][0];    // [64][65] fp32, 16.6KB < 36.8KB
#pragma unroll
    for (int nt = 0; nt < 3; nt++) {
      const int gnt = 6 + ns * 3 + nt;
      if ((gnt >> 2) == 2) {
        const int vcol = (gnt & 3) * 16 + l16;
#pragma unroll
        for (int mt = 0; mt < 2; mt++)
#pragma unroll
          for (int r = 0; r < 4; r++)
            vls[(mh * 32 + mt * 16 + quad * 4 + r) * 65 + vcol] = acc[mt][nt][r];
      }
    }
    __syncthreads();
    const int d = tid >> 2, seg = tid & 3;
    short8 p0, p1;
#pragma unroll
    for (int i = 0; i < 8; i++) p0[i] = (short)f2bf(vls[(seg * 16 + i) * 65 + d]);
#pragma unroll
    for (int i = 0; i < 8; i++) p1[i] = (short)f2bf(vls[(seg * 16 + 8 + i) * 65 + d]);
    ushort_t* dst = vT + ((size_t)(M0 >> 12) * HS + d) * TSEQ + (M0 & (TSEQ - 1)) + seg * 16;
    *(short8*)(dst)     = p0;
    *(short8*)(dst + 8) = p1;
  }
}

// ---------------- causal flash attention (MFMA), Bq=32, 8 waves ----------------
// grid B*128 = 512 blocks (big tiles first), 512 thr. wave w: q-tile w&1,
// key-split w>>1 (4-way, 64-key chunks). K/V frags direct from global,
// batch-issued at iter top. S^T layout: softmax per-lane row = l16.
__global__ __launch_bounds__(512) void attn_mfma(
    const ushort_t* __restrict__ q, const ushort_t* __restrict__ k,
    const ushort_t* __restrict__ vT, float* __restrict__ out)
{
  __shared__ __align__(16) float pool[8][1088];   // per-wave: P (16x72 bf16) then O-merge (16x68 f32)
  __shared__ float sM[8][16];
  __shared__ float sL[8][16];

  const int idx   = blockIdx.x;
  const int b     = idx & 3;
  const int j     = 127 - (idx >> 2);        // descending work order
  const int tbase = j * 32;
  const int w     = threadIdx.x >> 6;        // 0..7
  const int lane  = threadIdx.x & 63;
  const int l16   = lane & 15;
  const int quad  = lane >> 4;
  const int qt    = w & 1;                   // q-tile within block
  const int sp    = w >> 1;                  // key-split 0..3
  const int R0    = tbase + qt * 16;

  const ushort_t* qg = q  + ((size_t)b * TSEQ + R0) * HS;
  const ushort_t* kg = k  + (size_t)b * TSEQ * HS;
  const ushort_t* vg = vT + (size_t)b * HS * TSEQ;
  ushort_t* Pw = (ushort_t*)&pool[w][0];

  const short8 qf0 = *(const short8*)(qg + l16 * HS +      quad * 8);
  const short8 qf1 = *(const short8*)(qg + l16 * HS + 32 + quad * 8);

  f32x4 o[4];
#pragma unroll
  for (int dt = 0; dt < 4; dt++) o[dt] = (f32x4){0.f, 0.f, 0.f, 0.f};
  float mrow = -INFINITY, lrow = 0.f;        // per-lane row = l16

  const int nkt = (j >> 1) + 1;              // 64-key chunks incl. diagonal
  for (int kt = sp; kt < nkt; kt += 4) {
    const int k0 = kt * 64;
    // ---- batch-issue ALL K and V fragment loads for this chunk ----
    short8 kf[8], vf[8];
#pragma unroll
    for (int c = 0; c < 4; c++) {
      const ushort_t* kr = kg + (size_t)(k0 + c * 16 + l16) * HS + quad * 8;
      kf[c * 2]     = *(const short8*)(kr);
      kf[c * 2 + 1] = *(const short8*)(kr + 32);
    }
#pragma unroll
    for (int dt = 0; dt < 4; dt++) {
      const ushort_t* vr = vg + (size_t)(dt * 16 + l16) * TSEQ + k0 + quad * 8;
      vf[dt * 2]     = *(const short8*)(vr);
      vf[dt * 2 + 1] = *(const short8*)(vr + 32);
    }
    // ---- S^T = K Q^T  [64 keys x 16 rows]; C-layout: key=quad*4+r, row=l16 ----
    f32x4 sT[4];
#pragma unroll
    for (int c = 0; c < 4; c++) {
      sT[c] = (f32x4){0.f, 0.f, 0.f, 0.f};
      sT[c] = MFMA16(kf[c * 2],     qf0, sT[c]);
      sT[c] = MFMA16(kf[c * 2 + 1], qf1, sT[c]);
    }
    // ---- causal mask (diagonal chunks only; wave-uniform branch) ----
    if (k0 + 63 > R0) {
      const int row = R0 + l16;
#pragma unroll
      for (int c = 0; c < 4; c++) {
        const int key0 = k0 + c * 16 + quad * 4;
#pragma unroll
        for (int r = 0; r < 4; r++)
          sT[c][r] = (key0 + r <= row) ? sT[c][r] : -INFINITY;
      }
    }
    // ---- online softmax: within-lane tree + 2 cross-quad shuffles ----
    float t0 = fmaxf(fmaxf(sT[0][0], sT[0][1]), fmaxf(sT[0][2], sT[0][3]));
    float t1 = fmaxf(fmaxf(sT[1][0], sT[1][1]), fmaxf(sT[1][2], sT[1][3]));
    float t2 = fmaxf(fmaxf(sT[2][0], sT[2][1]), fmaxf(sT[2][2], sT[2][3]));
    float t3 = fmaxf(fmaxf(sT[3][0], sT[3][1]), fmaxf(sT[3][2], sT[3][3]));
    float tm = fmaxf(fmaxf(t0, t1), fmaxf(t2, t3));
    tm = fmaxf(tm, __shfl_xor(tm, 16));
    tm = fmaxf(tm, __shfl_xor(tm, 32));
    const float mn = fmaxf(mrow, tm);
    const float al = __expf(mrow - mn);      // first chunk: exp(-inf)=0
    mrow = mn;
    float ps = 0.f;
#pragma unroll
    for (int c = 0; c < 4; c++) {
#pragma unroll
      for (int r = 0; r < 4; r++) {
        sT[c][r] = __expf(sT[c][r] - mn);    // masked -inf -> 0
        ps += sT[c][r];
      }
    }
    ps += __shfl_xor(ps, 16);
    ps += __shfl_xor(ps, 32);
    lrow = lrow * al + ps;
    // ---- P -> LDS (packed b64 per c-tile), A-layout out ----
#pragma unroll
    for (int c = 0; c < 4; c++) {
      ushort4 pk;
      pk.x = f2bf(sT[c][0]); pk.y = f2bf(sT[c][1]);
      pk.z = f2bf(sT[c][2]); pk.w = f2bf(sT[c][3]);
      *(ushort4*)(Pw + l16 * 72 + c * 16 + quad * 4) = pk;
    }
    // ---- redistribute alpha to O-row indexing (row = quad*4+r) ----
    float alo[4];
#pragma unroll
    for (int r = 0; r < 4; r++) alo[r] = __shfl(al, quad * 4 + r);
#pragma unroll
    for (int dt = 0; dt < 4; dt++)
#pragma unroll
      for (int r = 0; r < 4; r++) o[dt][r] *= alo[r];
    // ---- O += P V ----
    const short8 pf0 = *(const short8*)(Pw + l16 * 72 +      quad * 8);
    const short8 pf1 = *(const short8*)(Pw + l16 * 72 + 32 + quad * 8);
#pragma unroll
    for (int dt = 0; dt < 4; dt++) {
      o[dt] = MFMA16(pf0, vf[dt * 2],     o[dt]);
      o[dt] = MFMA16(pf1, vf[dt * 2 + 1], o[dt]);
    }
  }

  // ---- merge 4 key-split partials per q-tile ----
  if (quad == 0) {
    sM[w][l16] = mrow;
    sL[w][l16] = lrow;
  }
  float* Ow = &pool[w][0];                   // overwrites Pw (wave-private)
#pragma unroll
  for (int dt = 0; dt < 4; dt++)
#pragma unroll
    for (int r = 0; r < 4; r++)
      Ow[(quad * 4 + r) * 68 + dt * 16 + l16] = o[dt][r];
  __syncthreads();

  const int row = threadIdx.x >> 4;          // 0..31
  const int d4  = threadIdx.x & 15;
  const int qtt = row >> 4, r16 = row & 15;
  float M = -INFINITY;
#pragma unroll
  for (int s = 0; s < 4; s++) M = fmaxf(M, sM[s * 2 + qtt][r16]);
  float den = 0.f;
  float4 num = make_float4(0.f, 0.f, 0.f, 0.f);
#pragma unroll
  for (int s = 0; s < 4; s++) {
    const int ww = s * 2 + qtt;
    const float a = __expf(sM[ww][r16] - M);   // zero-trip wave: weight 0
    den += sL[ww][r16] * a;
    const float4 val = *(const float4*)(&pool[ww][r16 * 68 + d4 * 4]);
    num.x += a * val.x; num.y += a * val.y; num.z += a * val.z; num.w += a * val.w;
  }
  const float inv = 1.f / den;
  *(float4*)(out + ((size_t)b * TSEQ + tbase + row) * HS + d4 * 4) =
      make_float4(num.x * inv, num.y * inv, num.z * inv, num.w * inv);
}

extern "C" void kernel_launch(void* const* d_in, const int* in_sizes, int n_in,
                              void* d_out, int out_size, void* d_ws, size_t ws_size,
                              hipStream_t stream) {
  const float* x  = (const float*)d_in[0];
  const float* Wq = (const float*)d_in[1];
  const float* Wk = (const float*)d_in[2];
  const float* Wv = (const float*)d_in[3];
  float* out = (float*)d_out;

  // ws: Wt (288 KB) | q (2 MB) | k (2 MB) | vT (2 MB)
  char* ws = (char*)d_ws;
  ushort_t* Wt = (ushort_t*)ws;
  ushort_t* qb = (ushort_t*)(ws + 294912);
  ushort_t* kb = (ushort_t*)(ws + 294912 + 2097152);
  ushort_t* vb = (ushort_t*)(ws + 294912 + 2 * 2097152);

  wprep<<<192, 256, 0, stream>>>(Wq, Wk, Wv, Wt);
  qkv_mfma<<<512, 256, 0, stream>>>(x, Wt, qb, kb, vb);
  attn_mfma<<<NBATCH * 128, 512, 0, stream>>>(qb, kb, vb, out);
}

// Round 5
// 158.809 us; speedup vs baseline: 1.2729x; 1.2185x over previous
//
#include <hip/hip_runtime.h>
#include <math.h>

typedef __attribute__((ext_vector_type(8))) short short8;
typedef __attribute__((ext_vector_type(4))) float f32x4;
typedef unsigned short ushort_t;

#define TSEQ   4096
#define NBATCH 4
#define DMODEL 768
#define HS     64

static __device__ __forceinline__ ushort_t f2bf(float f) {
  union { float f; unsigned u; } v; v.f = f;
  unsigned r = v.u + 0x7fffu + ((v.u >> 16) & 1u);   // RNE
  return (ushort_t)(r >> 16);
}
static __device__ __forceinline__ float bf2f(ushort_t u) {
  union { unsigned u; float f; } v; v.u = ((unsigned)u) << 16; return v.f;
}

#define MFMA16(a,b,c) __builtin_amdgcn_mfma_f32_16x16x32_bf16((a),(b),(c),0,0,0)

// ---------------- W prep (coalesced LDS transpose) ----------------
// grid 36 = 3 mats x 12 k-chunks of 64.  Wt[n'=m*64+n][k] bf16.
__global__ __launch_bounds__(256) void wprep(
    const float* __restrict__ Wq, const float* __restrict__ Wk,
    const float* __restrict__ Wv, ushort_t* __restrict__ Wt)
{
  __shared__ float lds[64 * 65];
  const int m = blockIdx.x / 12, kc = blockIdx.x % 12, k0 = kc * 64;
  const float* W = (m == 0) ? Wq : (m == 1) ? Wk : Wv;
  const int tid = threadIdx.x;
#pragma unroll
  for (int i = 0; i < 16; i++) {
    const int row = i * 4 + (tid >> 6), col = tid & 63;
    lds[row * 65 + col] = W[(size_t)(k0 + row) * HS + col];   // coalesced
  }
  __syncthreads();
#pragma unroll
  for (int i = 0; i < 16; i++) {
    const int n = i * 4 + (tid >> 6), kk = tid & 63;
    Wt[(size_t)(m * 64 + n) * DMODEL + k0 + kk] = f2bf(lds[kk * 65 + n]);
  }
}

// ---------------- QKV projection: M=64 x N=192, grid 256, 8 waves ----------
// wave w: mh=w>>1 (16 rows), ns=w&1 (96 cols). BK=64, dbuf LDS A-staging,
// x + Wt register-prefetched one iteration ahead. x read ONCE.
__global__ __launch_bounds__(512) void qkv_mfma(
    const float* __restrict__ x, const ushort_t* __restrict__ Wt,
    ushort_t* __restrict__ q, ushort_t* __restrict__ kO, ushort_t* __restrict__ vT)
{
  __shared__ __align__(16) ushort_t Abuf[2][64 * 72];   // 18.4 KB

  const int tid  = threadIdx.x;
  const int w    = tid >> 6, lane = tid & 63;
  const int l16  = lane & 15, quad = lane >> 4;
  const int mh   = w >> 1, ns = w & 1;
  const int M0   = blockIdx.x * 64;
  const float* xg = x + (size_t)M0 * DMODEL;

  const int srow = tid >> 3, scol = (tid & 7) * 8;      // staging: 8 thr/row
  const float* xs = xg + (size_t)srow * DMODEL + scol;
  const ushort_t* wb = Wt + (size_t)(ns * 96 + l16) * DMODEL + quad * 8;

  f32x4 acc[6];
#pragma unroll
  for (int nt = 0; nt < 6; nt++) acc[nt] = (f32x4){0.f, 0.f, 0.f, 0.f};

  float4 pr0 = *(const float4*)(xs);
  float4 pr1 = *(const float4*)(xs + 4);
  short8 bpre[12];
#pragma unroll
  for (int nt = 0; nt < 6; nt++)
#pragma unroll
    for (int kc = 0; kc < 2; kc++)
      bpre[nt * 2 + kc] = *(const short8*)(wb + (size_t)nt * 16 * DMODEL + kc * 32);

  for (int ks = 0; ks < DMODEL / 64; ks++) {
    ushort_t* Ab = &Abuf[ks & 1][0];
    {
      short8 p;
      p[0]=f2bf(pr0.x); p[1]=f2bf(pr0.y); p[2]=f2bf(pr0.z); p[3]=f2bf(pr0.w);
      p[4]=f2bf(pr1.x); p[5]=f2bf(pr1.y); p[6]=f2bf(pr1.z); p[7]=f2bf(pr1.w);
      *(short8*)(Ab + srow * 72 + scol) = p;
    }
    if (ks < DMODEL / 64 - 1) {                 // x prefetch (HBM latency hide)
      const float* xn = xs + (ks + 1) * 64;
      pr0 = *(const float4*)(xn);
      pr1 = *(const float4*)(xn + 4);
    }
    __syncthreads();                            // dbuf -> single barrier safe
    short8 bcur[12];
#pragma unroll
    for (int t = 0; t < 12; t++) bcur[t] = bpre[t];
    if (ks < DMODEL / 64 - 1) {                 // Wt prefetch (L2 latency hide)
#pragma unroll
      for (int nt = 0; nt < 6; nt++)
#pragma unroll
        for (int kc = 0; kc < 2; kc++)
          bpre[nt * 2 + kc] =
              *(const short8*)(wb + (size_t)nt * 16 * DMODEL + (ks + 1) * 64 + kc * 32);
    }
#pragma unroll
    for (int kc = 0; kc < 2; kc++) {
      const short8 af = *(const short8*)(Ab + (mh * 16 + l16) * 72 + kc * 32 + quad * 8);
#pragma unroll
      for (int nt = 0; nt < 6; nt++) acc[nt] = MFMA16(af, bcur[nt * 2 + kc], acc[nt]);
    }
  }

  // ---- epilogue: q/k direct; v via LDS transpose ----
#pragma unroll
  for (int nt = 0; nt < 6; nt++) {
    const int gnt = ns * 6 + nt;
    const int mat = gnt >> 2;                   // 0=q 1=k 2=v (wave-uniform)
    if (mat <= 1) {
      const int col = (gnt & 3) * 16 + l16;
#pragma unroll
      for (int r = 0; r < 4; r++) {
        const float val = acc[nt][r];
        const int trow = M0 + mh * 16 + quad * 4 + r;
        if (mat == 0) q [(size_t)trow * HS + col] = f2bf(val * 0.125f);
        else          kO[(size_t)trow * HS + col] = f2bf(val);
      }
    }
  }
  __syncthreads();                              // Abuf reads done; reuse as vls
  float* vls = (float*)&Abuf[0][0];             // [64][65] fp32 = 16.6 KB
  if (ns == 1) {
#pragma unroll
    for (int nt = 2; nt < 6; nt++) {            // gnt 8..11 = v
      const int vcol = ((ns * 6 + nt) & 3) * 16 + l16;
#pragma unroll
      for (int r = 0; r < 4; r++)
        vls[(mh * 16 + quad * 4 + r) * 65 + vcol] = acc[nt][r];
    }
  }
  __syncthreads();
  const int d = tid >> 3, seg = tid & 7;
  short8 pk;
#pragma unroll
  for (int i = 0; i < 8; i++) pk[i] = (short)f2bf(vls[(seg * 8 + i) * 65 + d]);
  *(short8*)(vT + ((size_t)(M0 >> 12) * HS + d) * TSEQ + (M0 & (TSEQ - 1)) + seg * 8) = pk;
}

// ---------------- attention pass 1: partial flash attention ----------------
// grid = 128 jt (descending) x B x KSPLIT(2) = 1024 blocks, 128 thr (2 waves).
// Block: 32 q-rows (wave w: 16), key-chunks of 64 with kt%2==s, shared LDS K/V
// (pitch 72, conflict-free), register-prefetched. Partials (m,l,O) -> ws.
#define KP 72
__global__ __launch_bounds__(128) void attn_part(
    const ushort_t* __restrict__ q, const ushort_t* __restrict__ k,
    const ushort_t* __restrict__ vT, float* __restrict__ ML, ushort_t* __restrict__ OP)
{
  __shared__ __align__(16) ushort_t sK[64 * KP];     // [key][d]
  __shared__ __align__(16) ushort_t sV[64 * KP];     // [d][key]
  __shared__ __align__(16) ushort_t sP[2][16 * KP];  // per-wave P

  const int idx  = blockIdx.x;
  const int s    = idx & 1;
  const int b    = (idx >> 1) & 3;
  const int jt   = 127 - (idx >> 3);           // descending work order
  const int tid  = threadIdx.x;
  const int w    = tid >> 6;
  const int lane = tid & 63;
  const int l16  = lane & 15, quad = lane >> 4;
  const int R0   = jt * 32 + w * 16;

  const ushort_t* qg = q  + (size_t)b * TSEQ * HS;
  const ushort_t* kg = k  + (size_t)b * TSEQ * HS;
  const ushort_t* vg = vT + (size_t)b * HS * TSEQ;

  // Q B-operand frags (q pre-scaled 1/8): B[k=d][n=qrow]
  const short8 qf0 = *(const short8*)(qg + (R0 + l16) * HS +      quad * 8);
  const short8 qf1 = *(const short8*)(qg + (R0 + l16) * HS + 32 + quad * 8);

  f32x4 o[4];
#pragma unroll
  for (int dt = 0; dt < 4; dt++) o[dt] = (f32x4){0.f, 0.f, 0.f, 0.f};
  float mrow = -INFINITY, lrow = 0.f;          // per-lane qrow = R0 + l16

  const int nkt = jt / 2 + 1;                  // 64-key chunks incl. diagonal
  short8 kpre[4], vpre[4];
  int kt = s;
  if (kt < nkt) {
    const int k0 = kt * 64;
#pragma unroll
    for (int i = 0; i < 4; i++) {
      const int c = i * 128 + tid, key = c >> 3, ch = c & 7;
      kpre[i] = *(const short8*)(kg + (size_t)(k0 + key) * HS + ch * 8);
      vpre[i] = *(const short8*)(vg + (size_t)key * TSEQ + k0 + ch * 8);
    }
  }
  for (; kt < nkt; kt += 2) {
    const int k0 = kt * 64;
    __syncthreads();                           // prior iter's LDS reads done
#pragma unroll
    for (int i = 0; i < 4; i++) {
      const int c = i * 128 + tid, key = c >> 3, ch = c & 7;
      *(short8*)(sK + key * KP + ch * 8) = kpre[i];
      *(short8*)(sV + key * KP + ch * 8) = vpre[i];
    }
    if (kt + 2 < nkt) {                        // prefetch next chunk
      const int kn = (kt + 2) * 64;
#pragma unroll
      for (int i = 0; i < 4; i++) {
        const int c = i * 128 + tid, key = c >> 3, ch = c & 7;
        kpre[i] = *(const short8*)(kg + (size_t)(kn + key) * HS + ch * 8);
        vpre[i] = *(const short8*)(vg + (size_t)key * TSEQ + kn + ch * 8);
      }
    }
    __syncthreads();                           // staged tile visible
    // ---- S^T = K Q^T : C[key = ct*16+quad*4+r][qrow = l16] ----
    f32x4 sT[4];
#pragma unroll
    for (int ct = 0; ct < 4; ct++) {
      sT[ct] = (f32x4){0.f, 0.f, 0.f, 0.f};
      const short8 kfa = *(const short8*)(sK + (ct * 16 + l16) * KP +      quad * 8);
      const short8 kfb = *(const short8*)(sK + (ct * 16 + l16) * KP + 32 + quad * 8);
      sT[ct] = MFMA16(kfa, qf0, sT[ct]);
      sT[ct] = MFMA16(kfb, qf1, sT[ct]);
    }
    if (k0 + 63 > R0) {                        // causal mask, diagonal only
      const int qrow = R0 + l16;
#pragma unroll
      for (int ct = 0; ct < 4; ct++)
#pragma unroll
        for (int r = 0; r < 4; r++)
          sT[ct][r] = (k0 + ct * 16 + quad * 4 + r <= qrow) ? sT[ct][r] : -INFINITY;
    }
    // ---- online softmax (per-lane row; 2 cross-quad shuffles) ----
    float tm = -INFINITY;
#pragma unroll
    for (int ct = 0; ct < 4; ct++)
#pragma unroll
      for (int r = 0; r < 4; r++) tm = fmaxf(tm, sT[ct][r]);
    tm = fmaxf(tm, __shfl_xor(tm, 16));
    tm = fmaxf(tm, __shfl_xor(tm, 32));
    const float mn = fmaxf(mrow, tm);
    const float al = __expf(mrow - mn);
    mrow = mn;
    float ps = 0.f;
#pragma unroll
    for (int ct = 0; ct < 4; ct++)
#pragma unroll
      for (int r = 0; r < 4; r++) { sT[ct][r] = __expf(sT[ct][r] - mn); ps += sT[ct][r]; }
    ps += __shfl_xor(ps, 16);
    ps += __shfl_xor(ps, 32);
    lrow = lrow * al + ps;
    // ---- P -> LDS (A-layout), O rescale, PV ----
    ushort_t* Pw = &sP[w][0];
#pragma unroll
    for (int ct = 0; ct < 4; ct++) {
      ushort4 pk;
      pk.x = f2bf(sT[ct][0]); pk.y = f2bf(sT[ct][1]);
      pk.z = f2bf(sT[ct][2]); pk.w = f2bf(sT[ct][3]);
      *(ushort4*)(Pw + l16 * KP + ct * 16 + quad * 4) = pk;
    }
    float alo[4];
#pragma unroll
    for (int r = 0; r < 4; r++) alo[r] = __shfl(al, quad * 4 + r);
#pragma unroll
    for (int dt = 0; dt < 4; dt++)
#pragma unroll
      for (int r = 0; r < 4; r++) o[dt][r] *= alo[r];
    const short8 pf0 = *(const short8*)(Pw + l16 * KP +      quad * 8);
    const short8 pf1 = *(const short8*)(Pw + l16 * KP + 32 + quad * 8);
#pragma unroll
    for (int dt = 0; dt < 4; dt++) {
      const short8 vfa = *(const short8*)(sV + (dt * 16 + l16) * KP +      quad * 8);
      const short8 vfb = *(const short8*)(sV + (dt * 16 + l16) * KP + 32 + quad * 8);
      o[dt] = MFMA16(pf0, vfa, o[dt]);
      o[dt] = MFMA16(pf1, vfb, o[dt]);
    }
  }

  // ---- write partials: ML fp32 [B][2][T][2], OP bf16 [B][2][T][64] ----
  const size_t base = ((size_t)(b * 2 + s) * TSEQ);
  if (quad == 0) {
    ML[(base + R0 + l16) * 2 + 0] = mrow;
    ML[(base + R0 + l16) * 2 + 1] = lrow;
  }
#pragma unroll
  for (int dt = 0; dt < 4; dt++)
#pragma unroll
    for (int r = 0; r < 4; r++)
      OP[(base + R0 + quad * 4 + r) * HS + dt * 16 + l16] = f2bf(o[dt][r]);
}

// ---------------- attention pass 2: merge the 2 key-splits ----------------
// grid 1024 x 256: block = 16 rows x 16 dim-groups.
__global__ __launch_bounds__(256) void attn_merge(
    const float* __restrict__ ML, const ushort_t* __restrict__ OP,
    float* __restrict__ out)
{
  const int row = blockIdx.x * 16 + (threadIdx.x >> 4);   // 0..16383
  const int b   = row >> 12, t = row & (TSEQ - 1);
  const int d0  = (threadIdx.x & 15) * 4;
  const size_t i0 = ((size_t)(b * 2 + 0) * TSEQ + t);
  const size_t i1 = ((size_t)(b * 2 + 1) * TSEQ + t);
  const float m0 = ML[i0 * 2], l0 = ML[i0 * 2 + 1];
  const float m1 = ML[i1 * 2], l1 = ML[i1 * 2 + 1];
  const float M  = fmaxf(m0, m1);
  const float a0 = __expf(m0 - M), a1 = __expf(m1 - M);   // m1=-inf -> a1=0
  const float inv = 1.f / (l0 * a0 + l1 * a1);
  const ushort4 u0 = *(const ushort4*)(OP + i0 * HS + d0);
  const ushort4 u1 = *(const ushort4*)(OP + i1 * HS + d0);
  float4 res;
  res.x = (a0 * bf2f(u0.x) + a1 * bf2f(u1.x)) * inv;
  res.y = (a0 * bf2f(u0.y) + a1 * bf2f(u1.y)) * inv;
  res.z = (a0 * bf2f(u0.z) + a1 * bf2f(u1.z)) * inv;
  res.w = (a0 * bf2f(u0.w) + a1 * bf2f(u1.w)) * inv;
  *(float4*)(out + (size_t)row * HS + d0) = res;
}

extern "C" void kernel_launch(void* const* d_in, const int* in_sizes, int n_in,
                              void* d_out, int out_size, void* d_ws, size_t ws_size,
                              hipStream_t stream) {
  const float* x  = (const float*)d_in[0];
  const float* Wq = (const float*)d_in[1];
  const float* Wk = (const float*)d_in[2];
  const float* Wv = (const float*)d_in[3];
  float* out = (float*)d_out;

  // ws: Wt 288K | q 2M | k 2M | vT 2M | ML 256K | OP 4M   (total ~10.5 MB)
  char* ws = (char*)d_ws;
  ushort_t* Wt = (ushort_t*)ws;
  ushort_t* qb = (ushort_t*)(ws + 294912);
  ushort_t* kb = (ushort_t*)(ws + 294912 + 2097152);
  ushort_t* vb = (ushort_t*)(ws + 294912 + 2 * 2097152);
  float*    ml = (float*)   (ws + 294912 + 3 * 2097152);
  ushort_t* op = (ushort_t*)(ws + 294912 + 3 * 2097152 + 262144);

  wprep<<<36, 256, 0, stream>>>(Wq, Wk, Wv, Wt);
  qkv_mfma<<<(NBATCH * TSEQ) / 64, 512, 0, stream>>>(x, Wt, qb, kb, vb);
  attn_part<<<1024, 128, 0, stream>>>(qb, kb, vb, ml, op);
  attn_merge<<<1024, 256, 0, stream>>>(ml, op, out);
}

// Round 6
// 148.677 us; speedup vs baseline: 1.3596x; 1.0681x over previous
//
#include <hip/hip_runtime.h>
#include <math.h>

typedef __attribute__((ext_vector_type(8))) short short8;
typedef __attribute__((ext_vector_type(4))) float f32x4;
typedef unsigned short ushort_t;

#define TSEQ   4096
#define NBATCH 4
#define DMODEL 768
#define HS     64
#define KSPLIT 4

static __device__ __forceinline__ ushort_t f2bf(float f) {
  union { float f; unsigned u; } v; v.f = f;
  unsigned r = v.u + 0x7fffu + ((v.u >> 16) & 1u);   // RNE
  return (ushort_t)(r >> 16);
}
static __device__ __forceinline__ float bf2f(ushort_t u) {
  union { unsigned u; float f; } v; v.u = ((unsigned)u) << 16; return v.f;
}

#define MFMA16(a,b,c) __builtin_amdgcn_mfma_f32_16x16x32_bf16((a),(b),(c),0,0,0)

// ---------------- W prep (coalesced LDS transpose) ----------------
// grid 36 = 3 mats x 12 k-chunks of 64.  Wt[n'=m*64+n][k] bf16.
__global__ __launch_bounds__(256) void wprep(
    const float* __restrict__ Wq, const float* __restrict__ Wk,
    const float* __restrict__ Wv, ushort_t* __restrict__ Wt)
{
  __shared__ float lds[64 * 65];
  const int m = blockIdx.x / 12, kc = blockIdx.x % 12, k0 = kc * 64;
  const float* W = (m == 0) ? Wq : (m == 1) ? Wk : Wv;
  const int tid = threadIdx.x;
#pragma unroll
  for (int i = 0; i < 16; i++) {
    const int row = i * 4 + (tid >> 6), col = tid & 63;
    lds[row * 65 + col] = W[(size_t)(k0 + row) * HS + col];   // coalesced
  }
  __syncthreads();
#pragma unroll
  for (int i = 0; i < 16; i++) {
    const int n = i * 4 + (tid >> 6), kk = tid & 63;
    Wt[(size_t)(m * 64 + n) * DMODEL + k0 + kk] = f2bf(lds[kk * 65 + n]);
  }
}

// ---------------- QKV projection: M=32 x N=192, grid 512 (2 blocks/CU) -----
// 4 waves: mh=w>>1 (16 rows), ns=w&1 (96 cols). BK=64, dbuf LDS A-staging,
// x + Wt register-prefetched one iteration ahead. launch_bounds(256,2) keeps
// ~256-VGPR budget so the 12-frag B-prefetch stays resident (round-5 fix).
__global__ __launch_bounds__(256, 2) void qkv_mfma(
    const float* __restrict__ x, const ushort_t* __restrict__ Wt,
    ushort_t* __restrict__ q, ushort_t* __restrict__ kO, ushort_t* __restrict__ vT)
{
  __shared__ __align__(16) ushort_t Abuf[2][32 * 72];   // 9.2 KB

  const int tid  = threadIdx.x;
  const int w    = tid >> 6, lane = tid & 63;
  const int l16  = lane & 15, quad = lane >> 4;
  const int mh   = w >> 1, ns = w & 1;
  const int M0   = blockIdx.x * 32;
  const float* xg = x + (size_t)M0 * DMODEL;

  const int srow = tid >> 3, scol = (tid & 7) * 8;      // staging: 8 thr/row
  const float* xs = xg + (size_t)srow * DMODEL + scol;
  const ushort_t* wb = Wt + (size_t)(ns * 96 + l16) * DMODEL + quad * 8;

  f32x4 acc[6];
#pragma unroll
  for (int nt = 0; nt < 6; nt++) acc[nt] = (f32x4){0.f, 0.f, 0.f, 0.f};

  float4 pr0 = *(const float4*)(xs);
  float4 pr1 = *(const float4*)(xs + 4);
  short8 bpre[12];
#pragma unroll
  for (int nt = 0; nt < 6; nt++)
#pragma unroll
    for (int kc = 0; kc < 2; kc++)
      bpre[nt * 2 + kc] = *(const short8*)(wb + (size_t)nt * 16 * DMODEL + kc * 32);

  for (int ks = 0; ks < DMODEL / 64; ks++) {
    ushort_t* Ab = &Abuf[ks & 1][0];
    {
      short8 p;
      p[0]=f2bf(pr0.x); p[1]=f2bf(pr0.y); p[2]=f2bf(pr0.z); p[3]=f2bf(pr0.w);
      p[4]=f2bf(pr1.x); p[5]=f2bf(pr1.y); p[6]=f2bf(pr1.z); p[7]=f2bf(pr1.w);
      *(short8*)(Ab + srow * 72 + scol) = p;
    }
    if (ks < DMODEL / 64 - 1) {                 // x prefetch (HBM latency hide)
      const float* xn = xs + (ks + 1) * 64;
      pr0 = *(const float4*)(xn);
      pr1 = *(const float4*)(xn + 4);
    }
    __syncthreads();                            // dbuf -> single barrier safe
    short8 bcur[12];
#pragma unroll
    for (int t = 0; t < 12; t++) bcur[t] = bpre[t];
    if (ks < DMODEL / 64 - 1) {                 // Wt prefetch (L2 latency hide)
#pragma unroll
      for (int nt = 0; nt < 6; nt++)
#pragma unroll
        for (int kc = 0; kc < 2; kc++)
          bpre[nt * 2 + kc] =
              *(const short8*)(wb + (size_t)nt * 16 * DMODEL + (ks + 1) * 64 + kc * 32);
    }
#pragma unroll
    for (int kc = 0; kc < 2; kc++) {
      const short8 af = *(const short8*)(Ab + (mh * 16 + l16) * 72 + kc * 32 + quad * 8);
#pragma unroll
      for (int nt = 0; nt < 6; nt++) acc[nt] = MFMA16(af, bcur[nt * 2 + kc], acc[nt]);
    }
  }

  // ---- epilogue: q/k direct; v via LDS transpose ----
#pragma unroll
  for (int nt = 0; nt < 6; nt++) {
    const int gnt = ns * 6 + nt;
    const int mat = gnt >> 2;                   // 0=q 1=k 2=v (wave-uniform)
    if (mat <= 1) {
      const int col = (gnt & 3) * 16 + l16;
#pragma unroll
      for (int r = 0; r < 4; r++) {
        const float val = acc[nt][r];
        const int trow = M0 + mh * 16 + quad * 4 + r;
        if (mat == 0) q [(size_t)trow * HS + col] = f2bf(val * 0.125f);
        else          kO[(size_t)trow * HS + col] = f2bf(val);
      }
    }
  }
  __syncthreads();                              // Abuf reads done; reuse as vls
  float* vls = (float*)&Abuf[0][0];             // [32][65] fp32 = 8.3 KB
  if (ns == 1) {
#pragma unroll
    for (int nt = 2; nt < 6; nt++) {            // gnt 8..11 = v
      const int vcol = ((ns * 6 + nt) & 3) * 16 + l16;
#pragma unroll
      for (int r = 0; r < 4; r++)
        vls[(mh * 16 + quad * 4 + r) * 65 + vcol] = acc[nt][r];
    }
  }
  __syncthreads();
  const int d = tid >> 2, seg = tid & 3;        // 64 dims x 4 segs of 8 t
  short8 pk;
#pragma unroll
  for (int i = 0; i < 8; i++) pk[i] = (short)f2bf(vls[(seg * 8 + i) * 65 + d]);
  *(short8*)(vT + ((size_t)(M0 >> 12) * HS + d) * TSEQ + (M0 & (TSEQ - 1)) + seg * 8) = pk;
}

// ---------------- attention pass 1: partial flash attention ----------------
// grid = 128 jt (descending) x B x KSPLIT(4) = 2048 blocks, 128 thr (2 waves).
// Block: 32 q-rows (wave w: 16), 64-key chunks with kt%4==s, shared LDS K/V
// (pitch 72), register-prefetched. Partials (m,l,O) -> ws.
#define KP 72
__global__ __launch_bounds__(128) void attn_part(
    const ushort_t* __restrict__ q, const ushort_t* __restrict__ k,
    const ushort_t* __restrict__ vT, float* __restrict__ ML, ushort_t* __restrict__ OP)
{
  __shared__ __align__(16) ushort_t sK[64 * KP];     // [key][d]
  __shared__ __align__(16) ushort_t sV[64 * KP];     // [d][key]
  __shared__ __align__(16) ushort_t sP[2][16 * KP];  // per-wave P

  const int idx  = blockIdx.x;
  const int s    = idx & 3;
  const int b    = (idx >> 2) & 3;
  const int jt   = 127 - (idx >> 4);           // descending work order
  const int tid  = threadIdx.x;
  const int w    = tid >> 6;
  const int lane = tid & 63;
  const int l16  = lane & 15, quad = lane >> 4;
  const int R0   = jt * 32 + w * 16;

  const ushort_t* qg = q  + (size_t)b * TSEQ * HS;
  const ushort_t* kg = k  + (size_t)b * TSEQ * HS;
  const ushort_t* vg = vT + (size_t)b * HS * TSEQ;

  // Q B-operand frags (q pre-scaled 1/8): B[k=d][n=qrow]
  const short8 qf0 = *(const short8*)(qg + (R0 + l16) * HS +      quad * 8);
  const short8 qf1 = *(const short8*)(qg + (R0 + l16) * HS + 32 + quad * 8);

  f32x4 o[4];
#pragma unroll
  for (int dt = 0; dt < 4; dt++) o[dt] = (f32x4){0.f, 0.f, 0.f, 0.f};
  float mrow = -INFINITY, lrow = 0.f;          // per-lane qrow = R0 + l16

  const int nkt = jt / 2 + 1;                  // 64-key chunks incl. diagonal
  short8 kpre[4], vpre[4];
  int kt = s;
  if (kt < nkt) {
    const int k0 = kt * 64;
#pragma unroll
    for (int i = 0; i < 4; i++) {
      const int c = i * 128 + tid, key = c >> 3, ch = c & 7;
      kpre[i] = *(const short8*)(kg + (size_t)(k0 + key) * HS + ch * 8);
      vpre[i] = *(const short8*)(vg + (size_t)key * TSEQ + k0 + ch * 8);
    }
  }
  for (; kt < nkt; kt += KSPLIT) {
    const int k0 = kt * 64;
    __syncthreads();                           // prior iter's LDS reads done
#pragma unroll
    for (int i = 0; i < 4; i++) {
      const int c = i * 128 + tid, key = c >> 3, ch = c & 7;
      *(short8*)(sK + key * KP + ch * 8) = kpre[i];
      *(short8*)(sV + key * KP + ch * 8) = vpre[i];
    }
    if (kt + KSPLIT < nkt) {                   // prefetch next chunk
      const int kn = (kt + KSPLIT) * 64;
#pragma unroll
      for (int i = 0; i < 4; i++) {
        const int c = i * 128 + tid, key = c >> 3, ch = c & 7;
        kpre[i] = *(const short8*)(kg + (size_t)(kn + key) * HS + ch * 8);
        vpre[i] = *(const short8*)(vg + (size_t)key * TSEQ + kn + ch * 8);
      }
    }
    __syncthreads();                           // staged tile visible
    // ---- S^T = K Q^T : C[key = ct*16+quad*4+r][qrow = l16] ----
    f32x4 sT[4];
#pragma unroll
    for (int ct = 0; ct < 4; ct++) {
      sT[ct] = (f32x4){0.f, 0.f, 0.f, 0.f};
      const short8 kfa = *(const short8*)(sK + (ct * 16 + l16) * KP +      quad * 8);
      const short8 kfb = *(const short8*)(sK + (ct * 16 + l16) * KP + 32 + quad * 8);
      sT[ct] = MFMA16(kfa, qf0, sT[ct]);
      sT[ct] = MFMA16(kfb, qf1, sT[ct]);
    }
    if (k0 + 63 > R0) {                        // causal mask, diagonal only
      const int qrow = R0 + l16;
#pragma unroll
      for (int ct = 0; ct < 4; ct++)
#pragma unroll
        for (int r = 0; r < 4; r++)
          sT[ct][r] = (k0 + ct * 16 + quad * 4 + r <= qrow) ? sT[ct][r] : -INFINITY;
    }
    // ---- online softmax (per-lane row; 2 cross-quad shuffles) ----
    float tm = -INFINITY;
#pragma unroll
    for (int ct = 0; ct < 4; ct++)
#pragma unroll
      for (int r = 0; r < 4; r++) tm = fmaxf(tm, sT[ct][r]);
    tm = fmaxf(tm, __shfl_xor(tm, 16));
    tm = fmaxf(tm, __shfl_xor(tm, 32));
    const float mn = fmaxf(mrow, tm);
    const float al = __expf(mrow - mn);
    mrow = mn;
    float ps = 0.f;
#pragma unroll
    for (int ct = 0; ct < 4; ct++)
#pragma unroll
      for (int r = 0; r < 4; r++) { sT[ct][r] = __expf(sT[ct][r] - mn); ps += sT[ct][r]; }
    ps += __shfl_xor(ps, 16);
    ps += __shfl_xor(ps, 32);
    lrow = lrow * al + ps;
    // ---- P -> LDS (A-layout), O rescale, PV ----
    ushort_t* Pw = &sP[w][0];
#pragma unroll
    for (int ct = 0; ct < 4; ct++) {
      ushort4 pk;
      pk.x = f2bf(sT[ct][0]); pk.y = f2bf(sT[ct][1]);
      pk.z = f2bf(sT[ct][2]); pk.w = f2bf(sT[ct][3]);
      *(ushort4*)(Pw + l16 * KP + ct * 16 + quad * 4) = pk;
    }
    float alo[4];
#pragma unroll
    for (int r = 0; r < 4; r++) alo[r] = __shfl(al, quad * 4 + r);
#pragma unroll
    for (int dt = 0; dt < 4; dt++)
#pragma unroll
      for (int r = 0; r < 4; r++) o[dt][r] *= alo[r];
    const short8 pf0 = *(const short8*)(Pw + l16 * KP +      quad * 8);
    const short8 pf1 = *(const short8*)(Pw + l16 * KP + 32 + quad * 8);
#pragma unroll
    for (int dt = 0; dt < 4; dt++) {
      const short8 vfa = *(const short8*)(sV + (dt * 16 + l16) * KP +      quad * 8);
      const short8 vfb = *(const short8*)(sV + (dt * 16 + l16) * KP + 32 + quad * 8);
      o[dt] = MFMA16(pf0, vfa, o[dt]);
      o[dt] = MFMA16(pf1, vfb, o[dt]);
    }
  }

  // ---- write partials: ML fp32 [B][KSPLIT][T][2], OP bf16 [B][KSPLIT][T][64] ----
  const size_t base = ((size_t)(b * KSPLIT + s) * TSEQ);
  if (quad == 0) {
    ML[(base + R0 + l16) * 2 + 0] = mrow;
    ML[(base + R0 + l16) * 2 + 1] = lrow;
  }
#pragma unroll
  for (int dt = 0; dt < 4; dt++)
#pragma unroll
    for (int r = 0; r < 4; r++)
      OP[(base + R0 + quad * 4 + r) * HS + dt * 16 + l16] = f2bf(o[dt][r]);
}

// ---------------- attention pass 2: merge the KSPLIT partials ----------------
// grid 1024 x 256: block = 16 rows x 16 dim-groups.
__global__ __launch_bounds__(256) void attn_merge(
    const float* __restrict__ ML, const ushort_t* __restrict__ OP,
    float* __restrict__ out)
{
  const int row = blockIdx.x * 16 + (threadIdx.x >> 4);   // 0..16383
  const int b   = row >> 12, t = row & (TSEQ - 1);
  const int d0  = (threadIdx.x & 15) * 4;
  float m[KSPLIT], l[KSPLIT];
  float M = -INFINITY;
#pragma unroll
  for (int ss = 0; ss < KSPLIT; ss++) {
    const size_t i = ((size_t)(b * KSPLIT + ss) * TSEQ + t);
    m[ss] = ML[i * 2]; l[ss] = ML[i * 2 + 1];
    M = fmaxf(M, m[ss]);
  }
  float den = 0.f;
  float4 num = make_float4(0.f, 0.f, 0.f, 0.f);
#pragma unroll
  for (int ss = 0; ss < KSPLIT; ss++) {
    const float a = __expf(m[ss] - M);          // zero-trip split: weight 0
    den += l[ss] * a;
    const size_t i = ((size_t)(b * KSPLIT + ss) * TSEQ + t);
    const ushort4 u = *(const ushort4*)(OP + i * HS + d0);
    num.x += a * bf2f(u.x); num.y += a * bf2f(u.y);
    num.z += a * bf2f(u.z); num.w += a * bf2f(u.w);
  }
  const float inv = 1.f / den;
  *(float4*)(out + (size_t)row * HS + d0) =
      make_float4(num.x * inv, num.y * inv, num.z * inv, num.w * inv);
}

extern "C" void kernel_launch(void* const* d_in, const int* in_sizes, int n_in,
                              void* d_out, int out_size, void* d_ws, size_t ws_size,
                              hipStream_t stream) {
  const float* x  = (const float*)d_in[0];
  const float* Wq = (const float*)d_in[1];
  const float* Wk = (const float*)d_in[2];
  const float* Wv = (const float*)d_in[3];
  float* out = (float*)d_out;

  // ws: Wt 288K | q 2M | k 2M | vT 2M | ML 512K | OP 8M   (total ~15 MB)
  char* ws = (char*)d_ws;
  ushort_t* Wt = (ushort_t*)ws;
  ushort_t* qb = (ushort_t*)(ws + 294912);
  ushort_t* kb = (ushort_t*)(ws + 294912 + 2097152);
  ushort_t* vb = (ushort_t*)(ws + 294912 + 2 * 2097152);
  float*    ml = (float*)   (ws + 294912 + 3 * 2097152);
  ushort_t* op = (ushort_t*)(ws + 294912 + 3 * 2097152 + 524288);

  wprep<<<36, 256, 0, stream>>>(Wq, Wk, Wv, Wt);
  qkv_mfma<<<(NBATCH * TSEQ) / 32, 256, 0, stream>>>(x, Wt, qb, kb, vb);
  attn_part<<<128 * NBATCH * KSPLIT, 128, 0, stream>>>(qb, kb, vb, ml, op);
  attn_merge<<<1024, 256, 0, stream>>>(ml, op, out);
}